// Round 6
// baseline (180.277 us; speedup 1.0000x reference)
//
#include <hip/hip_runtime.h>
#include <stdint.h>

#define Bn 256
#define Tn 50
#define Mn 20
#define En 128
#define G3 384
#define MT 64
#define LDA 132

typedef float f32x4 __attribute__((ext_vector_type(4)));

__device__ __forceinline__ float sigmoidf(float x) {
    return 1.0f / (1.0f + __expf(-x));
}
__device__ __forceinline__ float tanh_safe(float a) {
    float ax = fabsf(a);
    float e2 = __expf(-2.0f * ax);
    return copysignf((1.0f - e2) / (1.0f + e2), a);
}

// ---------------------------------------------------------------------------
// Kernel 1: basket-mean gather -> ub [B*T][128]  (stored in d_out region)
// ---------------------------------------------------------------------------
__global__ __launch_bounds__(256) void gather_kernel(
    const int*   __restrict__ item_ids,
    const int*   __restrict__ basket_sizes,
    const float* __restrict__ emb,
    float* __restrict__ ub)
{
    const int bt   = blockIdx.x * 8 + (threadIdx.x >> 5);
    const int lane = threadIdx.x & 31;
    const int* ids = item_ids + (size_t)bt * Mn;
    float ax = 0.f, ay = 0.f, az = 0.f, aw = 0.f;
    #pragma unroll
    for (int m = 0; m < Mn; ++m) {
        const float4 v = *(const float4*)(emb + (size_t)ids[m] * En + lane * 4);
        ax += v.x; ay += v.y; az += v.z; aw += v.w;
    }
    const float inv = 1.0f / (float)basket_sizes[bt];
    *(float4*)(ub + (size_t)bt * En + lane * 4) =
        make_float4(ax * inv, ay * inv, az * inv, aw * inv);
}

// ---------------------------------------------------------------------------
// Kernel 2: xg = ub @ W_ih^T + b_ih.  1200 blocks (200 M x 6 N); 4x4 tile.
// ---------------------------------------------------------------------------
__global__ __launch_bounds__(256, 2) void gemm_kernel(
    const float* __restrict__ ub,
    const float* __restrict__ W_ih,
    const float* __restrict__ b_ih,
    float* __restrict__ xg)
{
    __shared__ float A[MT][LDA];
    __shared__ float Bt[64][LDA];

    const int tid  = threadIdx.x;
    const int mt   = blockIdx.x / 6;
    const int nc   = blockIdx.x % 6;
    const int row0 = mt * MT;
    const int col0 = nc * 64;

    {
        const int r = tid >> 2, seg = tid & 3;
        const float4* srcA = (const float4*)(ub + (size_t)(row0 + r) * En + seg * 32);
        const float4* srcB = (const float4*)(W_ih + (size_t)(col0 + r) * En + seg * 32);
        float4* dstA = (float4*)&A[r][seg * 32];
        float4* dstB = (float4*)&Bt[r][seg * 32];
        #pragma unroll
        for (int c = 0; c < 8; ++c) { dstA[c] = srcA[c]; dstB[c] = srcB[c]; }
    }
    __syncthreads();

    const int tx = tid & 15;
    const int ty = tid >> 4;

    float acc[4][4];
    #pragma unroll
    for (int i = 0; i < 4; ++i)
        #pragma unroll
        for (int u = 0; u < 4; ++u) acc[i][u] = 0.0f;

    #pragma unroll 4
    for (int k4 = 0; k4 < 32; ++k4) {
        const float4 av[4] = {
            *(const float4*)&A[ty +  0][k4*4], *(const float4*)&A[ty + 16][k4*4],
            *(const float4*)&A[ty + 32][k4*4], *(const float4*)&A[ty + 48][k4*4]};
        const float4 bv[4] = {
            *(const float4*)&Bt[tx +  0][k4*4], *(const float4*)&Bt[tx + 16][k4*4],
            *(const float4*)&Bt[tx + 32][k4*4], *(const float4*)&Bt[tx + 48][k4*4]};
        #pragma unroll
        for (int i = 0; i < 4; ++i)
            #pragma unroll
            for (int u = 0; u < 4; ++u) {
                acc[i][u] = fmaf(av[i].x, bv[u].x, acc[i][u]);
                acc[i][u] = fmaf(av[i].y, bv[u].y, acc[i][u]);
                acc[i][u] = fmaf(av[i].z, bv[u].z, acc[i][u]);
                acc[i][u] = fmaf(av[i].w, bv[u].w, acc[i][u]);
            }
    }

    float bias[4];
    #pragma unroll
    for (int u = 0; u < 4; ++u) bias[u] = b_ih[col0 + tx + 16*u];
    #pragma unroll
    for (int i = 0; i < 4; ++i) {
        const size_t rowoff = (size_t)(row0 + ty + 16*i) * G3;
        #pragma unroll
        for (int u = 0; u < 4; ++u)
            xg[rowoff + col0 + tx + 16*u] = acc[i][u] + bias[u];
    }
}

// ---------------------------------------------------------------------------
// Kernel 3: sequential GRU. 256 blocks x 256 threads (4 waves, 1 wave/SIMD).
//
// ROUND-6: counters proved weights were NEVER VGPR-resident (VGPR 68-72 every
// round, WRITE_SIZE flat = no scratch spill => compiler re-streams 196 KB of
// W_hh from L2 every step; VALUBusy*cyc accounts for the ~600 issue cyc, the
// other ~1500 cyc/step is that stream at the L2 port ceiling).  At
// launch_bounds(512,2) the allocator is pressure-driven and remats; all pin
// hacks failed.  Fix: move to the NO-pressure regime.  256 threads -> 1
// wave/SIMD -> launch_bounds(256,1) -> 512-VGPR budget.  Thread (j=tid>>1,
// s=tid&1) owns gate rows {j,128+j,256+j}, cols [s*64,s*64+64) = 192 weights
// = 48 f32x4 (~240 VGPR total incl. working set) -> zero motive to remat.
// Reduce = ONE DPP xor-1.  Barrier spans 4 waves.  Per-SIMD FMA issue/step
// unchanged (192 inst x 2 cyc).  Success signature: VGPR_Count >= ~200.
// ---------------------------------------------------------------------------
__global__ __launch_bounds__(256, 1) void gru_kernel(
    const int*   __restrict__ lengths,
    const float* __restrict__ W_hh,
    const float* __restrict__ b_hh,
    const float* __restrict__ h0,
    const float* __restrict__ xg,
    float* __restrict__ out_dyn,
    float* __restrict__ out_h)
{
    extern __shared__ float smem[];
    float* hs  = smem;          // [2][En] double-buffered h
    float* sxg = smem + 2 * En; // [Tn*G3] staged x-gates (76.8 KB)

    const int tid = threadIdx.x;
    const int b   = blockIdx.x;
    const int j   = tid >> 1;        // [0,128)
    const int s   = tid & 1;         // {0,1} — lane-bit0 pair for DPP reduce

    const int len = lengths[b];
    const float* xgb = xg + (size_t)b * Tn * G3;
    float* outb = out_dyn + (size_t)b * Tn * En;

    // ---- one-time stage: xg[b] -> LDS (coalesced float4; only len rows) ----
    {
        const float4* src = (const float4*)xgb;
        float4* dst = (float4*)sxg;
        const int nv4 = len * (G3 / 4);      // <= 4800
        for (int i = tid; i < nv4; i += 256) dst[i] = src[i];
    }

    // Weight fragments: 3 gate rows x 64 cols = 48 f32x4, register-resident.
    f32x4 w0[16], w1[16], w2[16];
    {
        const f32x4* p0 = (const f32x4*)(W_hh + (size_t)(0*En + j) * En + s * 64);
        const f32x4* p1 = (const f32x4*)(W_hh + (size_t)(1*En + j) * En + s * 64);
        const f32x4* p2 = (const f32x4*)(W_hh + (size_t)(2*En + j) * En + s * 64);
        #pragma unroll
        for (int c = 0; c < 16; ++c) { w0[c] = p0[c]; w1[c] = p1[c]; w2[c] = p2[c]; }
    }

    const float br = b_hh[j], bz = b_hh[En + j], bn = b_hh[2*En + j];
    float hprev = h0[(size_t)b * En + j];
    if (s == 0) hs[j] = hprev;
    __syncthreads();   // one-time full drain: staging + hs[0] visible

    int cur = 0;
    for (int t = 0; t < len; ++t) {
        // x-gates from LDS — issued early, consumed after the dots
        const float x0r = sxg[t*G3 + j];
        const float x0z = sxg[t*G3 + En + j];
        const float x0n = sxg[t*G3 + 2*En + j];

        // partial dots over this thread's 64-col K-slice.  Per ds_read the 64
        // lanes hit only 2 distinct addresses (s=0/s=1) -> 2-way = free.
        const f32x4* h4 = ((const f32x4*)(hs + cur * En)) + s * 16;
        float a0 = 0.f, a1 = 0.f, a2 = 0.f;
        #pragma unroll
        for (int c = 0; c < 16; ++c) {
            const f32x4 hv = h4[c];
            a0 = fmaf(w0[c].x, hv.x, a0); a0 = fmaf(w0[c].y, hv.y, a0);
            a0 = fmaf(w0[c].z, hv.z, a0); a0 = fmaf(w0[c].w, hv.w, a0);
            a1 = fmaf(w1[c].x, hv.x, a1); a1 = fmaf(w1[c].y, hv.y, a1);
            a1 = fmaf(w1[c].z, hv.z, a1); a1 = fmaf(w1[c].w, hv.w, a1);
            a2 = fmaf(w2[c].x, hv.x, a2); a2 = fmaf(w2[c].y, hv.y, a2);
            a2 = fmaf(w2[c].z, hv.z, a2); a2 = fmaf(w2[c].w, hv.w, a2);
        }

        // single DPP butterfly over the s-pair (lane bit 0)
        {
            int t0 = __builtin_amdgcn_update_dpp(0, __float_as_int(a0),
                                                 0xB1, 0xF, 0xF, true);
            a0 += __int_as_float(t0);
            int u0 = __builtin_amdgcn_update_dpp(0, __float_as_int(a1),
                                                 0xB1, 0xF, 0xF, true);
            a1 += __int_as_float(u0);
            int v0 = __builtin_amdgcn_update_dpp(0, __float_as_int(a2),
                                                 0xB1, 0xF, 0xF, true);
            a2 += __int_as_float(v0);
        }

        // gates — computed redundantly by both s-lanes
        const float r = sigmoidf(x0r + br + a0);
        const float z = sigmoidf(x0z + bz + a1);
        const float n = tanh_safe(x0n + r * (bn + a2));
        const float hnew = (1.0f - z) * n + z * hprev;

        if (s == 0) {
            hs[(cur ^ 1) * En + j] = hnew;  // write the OTHER buffer
            outb[t*En + j] = hnew;          // fire-and-forget store
        }
        // Raw barrier: drain LDS only; the outb store stays in flight.
        asm volatile("s_waitcnt lgkmcnt(0)" ::: "memory");
        __builtin_amdgcn_s_barrier();
        __builtin_amdgcn_sched_barrier(0);

        hprev = hnew;
        cur ^= 1;
    }

    if (s == 0) {
        for (int t = len; t < Tn; ++t) outb[t*En + j] = 0.0f;
        out_h[(size_t)b * En + j] = hprev;
    }
}

extern "C" void kernel_launch(void* const* d_in, const int* in_sizes, int n_in,
                              void* d_out, int out_size, void* d_ws, size_t ws_size,
                              hipStream_t stream) {
    const int*   item_ids     = (const int*)d_in[0];
    const int*   basket_sizes = (const int*)d_in[1];
    const int*   lengths      = (const int*)d_in[2];
    const float* emb          = (const float*)d_in[3];
    const float* W_ih         = (const float*)d_in[4];
    const float* W_hh         = (const float*)d_in[5];
    const float* b_ih         = (const float*)d_in[6];
    const float* b_hh         = (const float*)d_in[7];
    const float* h0           = (const float*)d_in[8];
    float* out = (float*)d_out;
    float* xg  = (float*)d_ws;   // 19.7 MB
    float* ub  = out;            // reuse out_dyn region; overwritten by gru later

    // Allow >64KB dynamic LDS for gru_kernel (HW max 160 KB on gfx950).
    static bool lds_attr_set = false;
    if (!lds_attr_set) {
        (void)hipFuncSetAttribute((const void*)gru_kernel,
                                  hipFuncAttributeMaxDynamicSharedMemorySize,
                                  (2 * En + Tn * G3) * (int)sizeof(float));
        lds_attr_set = true;
    }

    gather_kernel<<<(Bn * Tn) / 8, 256, 0, stream>>>(item_ids, basket_sizes, emb, ub);
    gemm_kernel<<<1200, 256, 0, stream>>>(ub, W_ih, b_ih, xg);
    gru_kernel<<<Bn, 256, (2 * En + Tn * G3) * sizeof(float), stream>>>(
        lengths, W_hh, b_hh, h0, xg, out, out + (size_t)Bn * Tn * En);
}